// Round 8
// baseline (161.083 us; speedup 1.0000x reference)
//
#include <hip/hip_runtime.h>

#define BB 16
#define CC 512
#define NN 2048
#define MAXH 70
#define MAXW 40
#define NPIX (MAXH * MAXW)   // 2800
#define BIGC 1000000
#define G 4                  // planes per fill block (LDS = G*8KB = 32KB)

typedef float  f32x4 __attribute__((ext_vector_type(4)));
typedef int    i32x4 __attribute__((ext_vector_type(4)));
typedef unsigned int u32;

// async global->LDS DMA, 16B per lane, wave-uniform LDS base + lane*16
#define GLDS16(gp, lp) __builtin_amdgcn_global_load_lds( \
    (const __attribute__((address_space(1))) u32*)(gp),  \
    (__attribute__((address_space(3))) u32*)(lp), 16, 0, 0)

// ---------- Kernel 1: per-sample inverse map build (16 blocks) ----------
// srcmap[b, pix] = winning point index n, or -1.
// NumPy fancy-index semantics: negative indices wrap once (+= size) before
// mode='drop'; collisions resolve last-write-wins == largest n (atomicMax).
__global__ __launch_bounds__(256) void build_map_kernel(
    const int* __restrict__ ys, const int* __restrict__ xs,
    int* __restrict__ srcmap)
{
    const int b = blockIdx.x;
    const int tid = threadIdx.x;
    const int* __restrict__ y = ys + b * NN;
    const int* __restrict__ x = xs + b * NN;

    __shared__ int smap[NPIX];
    __shared__ int s0[256], s1[256], s2[256], s3[256];

    for (int p = tid; p < NPIX; p += 256) smap[p] = -1;

    int mny = BIGC, mxy = -BIGC, mnx = BIGC, mxx = -BIGC;
    for (int n = tid; n < NN; n += 256) {
        int yy = y[n];
        if (yy > -1) {
            int xx = x[n];
            mny = min(mny, yy); mxy = max(mxy, yy);
            mnx = min(mnx, xx); mxx = max(mxx, xx);
        }
    }
    s0[tid] = mny; s1[tid] = mxy; s2[tid] = mnx; s3[tid] = mxx;
    __syncthreads();
    for (int s = 128; s > 0; s >>= 1) {
        if (tid < s) {
            s0[tid] = min(s0[tid], s0[tid + s]);
            s1[tid] = max(s1[tid], s1[tid + s]);
            s2[tid] = min(s2[tid], s2[tid + s]);
            s3[tid] = max(s3[tid], s3[tid + s]);
        }
        __syncthreads();
    }
    const int min_y = s0[0], max_y = s1[0], min_x = s2[0], max_x = s3[0];
    const int h = max_y - min_y + 1;
    const int w = max_x - min_x + 1;
    const int trans = (w > h) ? 1 : 0;
    const int H2 = trans ? w : h;
    const int W2 = trans ? h : w;
    const int hd = H2 - MAXH;
    const int wd = W2 - MAXW;
    const int sy = (hd > 0) ? -((hd + 1) / 2) : ((1 - hd) / 2);
    const int sx = (wd > 0) ? -((wd + 1) / 2) : ((1 - wd) / 2);

    for (int n = tid; n < NN; n += 256) {
        int yy0 = y[n];
        if (yy0 <= -1) continue;
        int ry = yy0 - min_y;
        int rx = x[n] - min_x;
        int oy = (trans ? rx : ry) + sy;
        int ox = (trans ? ry : rx) + sx;
        if (oy < 0) oy += MAXH;            // numpy wrap (single; invalid pts excluded above)
        if (ox < 0) ox += MAXW;
        if (oy >= 0 && oy < MAXH && ox >= 0 && ox < MAXW)
            atomicMax(&smap[oy * MAXW + ox], n);
    }
    __syncthreads();

    int* __restrict__ g = srcmap + b * NPIX;
    for (int p = tid; p < NPIX; p += 256) g[p] = smap[p];
}

// ---------- Kernel 2: DMA-staged gather fill (512 thr, 32KB LDS) ----------
// 4 blocks/CU = 32 waves/CU (max). Staging via async global_load_lds (16B/lane,
// fire-and-forget); map int4 + backend loads issue while DMA is in flight;
// one vmcnt drain at the barrier.
__global__ __launch_bounds__(512) void fill_out_lds_kernel(
    const float* __restrict__ feat, const float* __restrict__ backend,
    const int* __restrict__ srcmap, float* __restrict__ out)
{
    const int grp = blockIdx.x;             // 0 .. BB*CC/G - 1
    const int gpb = CC / G;                 // groups per sample
    const int b  = grp / gpb;
    const int c0 = (grp - b * gpb) * G;
    const int tid = threadIdx.x;
    const int lane = tid & 63;
    const int wid  = tid >> 6;              // 8 waves

    __shared__ float sfeat[G * NN];         // 32 KB

    // issue async staging DMAs: wave w, iter i stages 1KB chunk (i*8 + w)
    const float* __restrict__ fsrc = feat + ((size_t)b * CC + c0) * NN;
    #pragma unroll
    for (int i = 0; i < 4; ++i) {
        const int chunk = i * 8 + wid;              // 0..31, 256 floats each
        GLDS16(fsrc + chunk * 256 + lane * 4,       // per-lane global src
               sfeat + chunk * 256);                // wave-uniform LDS base
    }

    // map + backend loads overlap with DMA
    const i32x4* __restrict__ smap4 = (const i32x4*)(srcmap + b * NPIX);
    const int p4a = tid;
    const int p4b = tid + 512;
    const bool hasB = (p4b < NPIX / 4);
    i32x4 sA = smap4[p4a];
    i32x4 sB = smap4[hasB ? p4b : 0];
    f32x4 bv = *(const f32x4*)(backend + c0);       // c0 % 4 == 0 -> 16B aligned

    __syncthreads();                                 // drains vmcnt(0): DMA + map done

    f32x4* __restrict__ obase = (f32x4*)(out + ((size_t)b * CC + c0) * NPIX);

    #pragma unroll
    for (int g = 0; g < G; ++g) {
        const float* sf = sfeat + g * NN;
        f32x4 v;
        v.x = (sA.x >= 0) ? sf[sA.x] : bv[g];
        v.y = (sA.y >= 0) ? sf[sA.y] : bv[g];
        v.z = (sA.z >= 0) ? sf[sA.z] : bv[g];
        v.w = (sA.w >= 0) ? sf[sA.w] : bv[g];
        __builtin_nontemporal_store(v, obase + (size_t)g * (NPIX / 4) + p4a);
    }
    if (hasB) {
        #pragma unroll
        for (int g = 0; g < G; ++g) {
            const float* sf = sfeat + g * NN;
            f32x4 v;
            v.x = (sB.x >= 0) ? sf[sB.x] : bv[g];
            v.y = (sB.y >= 0) ? sf[sB.y] : bv[g];
            v.z = (sB.z >= 0) ? sf[sB.z] : bv[g];
            v.w = (sB.w >= 0) ? sf[sB.w] : bv[g];
            __builtin_nontemporal_store(v, obase + (size_t)g * (NPIX / 4) + p4b);
        }
    }
}

// ---------- Fallback: fused single-kernel (passing round-3 version) ----------
__global__ __launch_bounds__(256) void fused_map_kernel(
    const float* __restrict__ feat, const float* __restrict__ backend,
    const int* __restrict__ ys, const int* __restrict__ xs,
    float* __restrict__ out)
{
    const int plane = blockIdx.x;
    const int b = plane >> 9;
    const int c = plane & (CC - 1);
    const int tid = threadIdx.x;
    const int* __restrict__ y = ys + b * NN;
    const int* __restrict__ x = xs + b * NN;

    __shared__ int smap[NPIX];
    __shared__ int s0[256], s1[256], s2[256], s3[256];

    for (int p = tid; p < NPIX; p += 256) smap[p] = -1;

    int mny = BIGC, mxy = -BIGC, mnx = BIGC, mxx = -BIGC;
    for (int n = tid; n < NN; n += 256) {
        int yy = y[n];
        if (yy > -1) {
            int xx = x[n];
            mny = min(mny, yy); mxy = max(mxy, yy);
            mnx = min(mnx, xx); mxx = max(mxx, xx);
        }
    }
    s0[tid] = mny; s1[tid] = mxy; s2[tid] = mnx; s3[tid] = mxx;
    __syncthreads();
    for (int s = 128; s > 0; s >>= 1) {
        if (tid < s) {
            s0[tid] = min(s0[tid], s0[tid + s]);
            s1[tid] = max(s1[tid], s1[tid + s]);
            s2[tid] = min(s2[tid], s2[tid + s]);
            s3[tid] = max(s3[tid], s3[tid + s]);
        }
        __syncthreads();
    }
    const int min_y = s0[0], max_y = s1[0], min_x = s2[0], max_x = s3[0];
    const int h = max_y - min_y + 1;
    const int w = max_x - min_x + 1;
    const int trans = (w > h) ? 1 : 0;
    const int H2 = trans ? w : h;
    const int W2 = trans ? h : w;
    const int hd = H2 - MAXH;
    const int wd = W2 - MAXW;
    const int sy = (hd > 0) ? -((hd + 1) / 2) : ((1 - hd) / 2);
    const int sx = (wd > 0) ? -((wd + 1) / 2) : ((1 - wd) / 2);

    for (int n = tid; n < NN; n += 256) {
        int yy0 = y[n];
        if (yy0 <= -1) continue;
        int ry = yy0 - min_y;
        int rx = x[n] - min_x;
        int oy = (trans ? rx : ry) + sy;
        int ox = (trans ? ry : rx) + sx;
        if (oy < 0) oy += MAXH;
        if (ox < 0) ox += MAXW;
        if (oy >= 0 && oy < MAXH && ox >= 0 && ox < MAXW)
            atomicMax(&smap[oy * MAXW + ox], n);
    }
    __syncthreads();

    const float bv = backend[c];
    const float* __restrict__ frow = feat + (size_t)plane * NN;
    f32x4* __restrict__ orow4 = (f32x4*)(out + (size_t)plane * NPIX);

    for (int p4 = tid; p4 < NPIX / 4; p4 += 256) {
        const int base = p4 * 4;
        int a0 = smap[base + 0];
        int a1 = smap[base + 1];
        int a2 = smap[base + 2];
        int a3 = smap[base + 3];
        f32x4 v;
        v.x = (a0 >= 0) ? frow[a0] : bv;
        v.y = (a1 >= 0) ? frow[a1] : bv;
        v.z = (a2 >= 0) ? frow[a2] : bv;
        v.w = (a3 >= 0) ? frow[a3] : bv;
        orow4[p4] = v;
    }
}

extern "C" void kernel_launch(void* const* d_in, const int* in_sizes, int n_in,
                              void* d_out, int out_size, void* d_ws, size_t ws_size,
                              hipStream_t stream) {
    const float* feat    = (const float*)d_in[0];   // [B, C, N] f32
    const float* backend = (const float*)d_in[1];   // [C, 1, 1] f32
    const int*   ys      = (const int*)d_in[2];     // [B, N] i32
    const int*   xs      = (const int*)d_in[3];     // [B, N] i32
    float* out = (float*)d_out;                     // [B, C, MAXH, MAXW] f32

    const size_t need = (size_t)BB * NPIX * sizeof(int);   // 179,200 B
    if (ws_size >= need) {
        int* srcmap = (int*)d_ws;
        build_map_kernel<<<BB, 256, 0, stream>>>(ys, xs, srcmap);
        fill_out_lds_kernel<<<BB * CC / G, 512, 0, stream>>>(feat, backend, srcmap, out);
    } else {
        fused_map_kernel<<<BB * CC, 256, 0, stream>>>(feat, backend, ys, xs, out);
    }
}